// Round 2
// baseline (272.805 us; speedup 1.0000x reference)
//
#include <hip/hip_runtime.h>
#include <cstdint>
#include <cstddef>

typedef unsigned short u16;
typedef unsigned int   u32;
typedef __attribute__((ext_vector_type(8))) short short8;
typedef __attribute__((ext_vector_type(4))) float f32x4;
typedef __attribute__((ext_vector_type(4))) u16   u16x4;

// ---------- bf16 helpers (RNE) ----------
__device__ __forceinline__ float bf2f(u16 u){
  u32 x = ((u32)u) << 16; float f; __builtin_memcpy(&f, &x, 4); return f;
}
__device__ __forceinline__ u16 f2bf(float f){
  u32 x; __builtin_memcpy(&x, &f, 4);
  x += 0x7fffu + ((x >> 16) & 1u);
  return (u16)(x >> 16);
}

__device__ __forceinline__ void gload_lds16(const u16* g, u16* l){
  __builtin_amdgcn_global_load_lds((const __attribute__((address_space(1))) void*)g,
                                   (__attribute__((address_space(3))) void*)l, 16, 0, 0);
}

// ---------- one-shot convert: features (3.2M f4) + all weights (90112 f4) ----------
__global__ void convert_all(const float* __restrict__ F,
                            const float* __restrict__ W1, const float* __restrict__ W2,
                            const float* __restrict__ W3, const float* __restrict__ Wd1,
                            const float* __restrict__ Wd2, const float* __restrict__ M1,
                            const float* __restrict__ M2,
                            u16* __restrict__ fB,
                            u16* __restrict__ W1b, u16* __restrict__ Wcb,
                            u16* __restrict__ Wd1b, u16* __restrict__ Wd2b,
                            u16* __restrict__ M1b, u16* __restrict__ M2b){
  int j = blockIdx.x * blockDim.x + threadIdx.x;
  const float* src; u16* dst;
  if (j < 3200000)            { src = F;   dst = fB; }
  else if ((j -= 3200000) < 16384) { src = W1;  dst = W1b; }
  else if ((j -= 16384) < 8192)    { src = W2;  dst = Wcb; }
  else if ((j -= 8192)  < 8192)    { src = W3;  dst = Wcb + 32768; }
  else if ((j -= 8192)  < 8192)    { src = Wd1; dst = Wd1b; }
  else if ((j -= 8192)  < 16384)   { src = Wd2; dst = Wd2b; }
  else if ((j -= 16384) < 16384)   { src = M1;  dst = M1b; }
  else { j -= 16384; if (j >= 16384) return; src = M2; dst = M2b; }
  float4 v = ((const float4*)src)[j];
  u16x4 o; o[0]=f2bf(v.x); o[1]=f2bf(v.y); o[2]=f2bf(v.z); o[3]=f2bf(v.w);
  ((u16x4*)dst)[j] = o;
}

// ---------- gather-mean over 20 sampled neighbors ----------
// 1 wave per node (4 nodes / 256-block); lane reads 8B (4 bf16) -> one dwordx2
// per wave covers the whole 512B row; indices loaded once, shfl-broadcast.
__global__ void gather_mean(const u32* __restrict__ rows, const int* __restrict__ idx,
                            u32* __restrict__ out, int nout){
  const int node = blockIdx.x * 4 + (threadIdx.x >> 6);
  const int lane = threadIdx.x & 63;
  if (node >= nout) return;
  const int* ip = idx + (size_t)node * 20;
  const int jv = (lane < 20) ? ip[lane] : 0;
  float a0=0.f, a1=0.f, a2=0.f, a3=0.f;
  #pragma unroll
  for (int s = 0; s < 20; ++s){
    const int j = __shfl(jv, s, 64);
    const uint2 u = *(const uint2*)(rows + (size_t)j * 128 + lane * 2);
    a0 += bf2f((u16)(u.x & 0xffffu)); a1 += bf2f((u16)(u.x >> 16));
    a2 += bf2f((u16)(u.y & 0xffffu)); a3 += bf2f((u16)(u.y >> 16));
  }
  const float inv = 0.05f;
  uint2 o;
  o.x = (u32)f2bf(a0*inv) | ((u32)f2bf(a1*inv) << 16);
  o.y = (u32)f2bf(a2*inv) | ((u32)f2bf(a3*inv) << 16);
  *(uint2*)(out + (size_t)node * 128 + lane * 2) = o;
}

// ---------- bf16 MFMA GEMM: C[M,N] = epi(A[M,K] @ B[N,K]^T) ----------
// 128x128 tile, BK=64, 4 waves (2x2 of 64x64), global_load_lds, double-buffered.
// EPI: 0=none 1=relu 2=tanh(x+bias) 3=x+bias
// OUT: 0=bf16 (ldc)  1=f32 (ldc)
// SWZ: 1 = XCD-chunked block swizzle for 64x64-tile grids (adj GEMM)
template<int EPI, int OUT, int SWZ>
__global__ __launch_bounds__(256)
void gemm_bt(const u16* __restrict__ A, const u16* __restrict__ B,
             void* __restrict__ C, int ldc, const float* __restrict__ bias,
             int M, int N, int K)
{
  __shared__ u16 As[2][8192];
  __shared__ u16 Bs[2][8192];
  const int tid  = threadIdx.x;
  const int lane = tid & 63;
  const int wave = tid >> 6;
  const int wm = wave >> 1, wn = wave & 1;
  int m0, n0;
  if (SWZ){
    // 4096 blocks = 8 XCDs x 8 M-rows x 64 N-cols; n fastest within an XCD.
    const int bid  = blockIdx.x;
    const int slot = bid >> 3;
    m0 = (((bid & 7) << 3) + (slot >> 6)) << 7;
    n0 = (slot & 63) << 7;
  } else { m0 = blockIdx.x << 7; n0 = blockIdx.y << 7; }
  const int nkt = K >> 6;

  f32x4 acc[4][4];
  #pragma unroll
  for (int a = 0; a < 4; ++a)
    #pragma unroll
    for (int b = 0; b < 4; ++b)
      acc[a][b] = (f32x4){0.f, 0.f, 0.f, 0.f};

  const int fbase = wave * 2048 + lane * 8;

  auto stage = [&](int buf, int kt){
    const int k0 = kt * 64;
    #pragma unroll
    for (int c = 0; c < 4; ++c){
      int f = fbase + c * 512;
      int r = f >> 6, cc = f & 63;
      int ra = m0 + r; if (ra >= M) ra = M - 1;     // row clamp (only GEMM1 needs it)
      gload_lds16(A + (size_t)ra * K + k0 + cc, &As[buf][wave * 2048 + c * 512]);
    }
    #pragma unroll
    for (int c = 0; c < 4; ++c){
      int f = fbase + c * 512;
      int r = f >> 6, cc = f & 63;
      gload_lds16(B + (size_t)(n0 + r) * K + k0 + cc, &Bs[buf][wave * 2048 + c * 512]);
    }
  };

  stage(0, 0);
  __syncthreads();
  int cur = 0;
  for (int kt = 0; kt < nkt; ++kt){
    if (kt + 1 < nkt) stage(cur ^ 1, kt + 1);
    const u16* as = As[cur];
    const u16* bs = Bs[cur];
    #pragma unroll
    for (int kk = 0; kk < 2; ++kk){
      const int ko = kk * 32 + (lane >> 4) * 8;
      short8 af[4], bq[4];
      #pragma unroll
      for (int mi = 0; mi < 4; ++mi)
        af[mi] = *(const short8*)(as + (wm * 64 + mi * 16 + (lane & 15)) * 64 + ko);
      #pragma unroll
      for (int ni = 0; ni < 4; ++ni)
        bq[ni] = *(const short8*)(bs + (wn * 64 + ni * 16 + (lane & 15)) * 64 + ko);
      #pragma unroll
      for (int mi = 0; mi < 4; ++mi)
        #pragma unroll
        for (int ni = 0; ni < 4; ++ni)
          acc[mi][ni] = __builtin_amdgcn_mfma_f32_16x16x32_bf16(af[mi], bq[ni], acc[mi][ni], 0, 0, 0);
    }
    __syncthreads();
    cur ^= 1;
  }

  // epilogue: C/D layout col = lane&15, row = (lane>>4)*4 + reg  [m89-verified]
  const int rbase = m0 + wm * 64 + ((lane >> 4) << 2);
  const int cbase = n0 + wn * 64 + (lane & 15);
  #pragma unroll
  for (int mi = 0; mi < 4; ++mi){
    #pragma unroll
    for (int ni = 0; ni < 4; ++ni){
      const int col = cbase + ni * 16;
      float bv = (EPI == 2 || EPI == 3) ? bias[col] : 0.f;
      #pragma unroll
      for (int r = 0; r < 4; ++r){
        const int row = rbase + mi * 16 + r;
        if (row < M){
          float v = acc[mi][ni][r];
          if (EPI == 1)      v = fmaxf(v, 0.f);
          else if (EPI == 2) v = tanhf(v + bv);
          else if (EPI == 3) v = v + bv;
          if (OUT == 0)      ((u16*)C)[(size_t)row * ldc + col] = f2bf(v);
          else               ((float*)C)[(size_t)row * ldc + col] = v;
        }
      }
    }
  }
}

// ---------- encoder GEMM + reparam fusion ----------
// mu = relu(A@W2^T), lv = relu(A@W3^T), h = eps*exp(lv)+mu
// A: agg2 [8192x256] bf16; Wcb: [W2;W3] stacked [256x256] bf16.
// Tile 128 rows x 128 cols, dual accumulators. Grid 64 blocks x 256 threads.
__global__ __launch_bounds__(256)
void gemm_enc(const u16* __restrict__ A, const u16* __restrict__ Wcb,
              const float* __restrict__ eps,
              float* __restrict__ outMu, float* __restrict__ outLv,
              u16* __restrict__ hB)
{
  __shared__ u16 As[2][8192];    // 128 x 64
  __shared__ u16 Bs[2][16384];   // 256 x 64  ([W2 rows; W3 rows])
  const int tid  = threadIdx.x;
  const int lane = tid & 63;
  const int wave = tid >> 6;
  const int wm = wave >> 1, wn = wave & 1;
  const int m0 = blockIdx.x << 7;
  const int K = 256;

  f32x4 accm[4][4], accl[4][4];
  #pragma unroll
  for (int a = 0; a < 4; ++a)
    #pragma unroll
    for (int b = 0; b < 4; ++b){
      accm[a][b] = (f32x4){0.f,0.f,0.f,0.f};
      accl[a][b] = (f32x4){0.f,0.f,0.f,0.f};
    }

  auto stage = [&](int buf, int kt){
    const int k0 = kt * 64;
    const int fa = wave * 2048 + lane * 8;
    #pragma unroll
    for (int c = 0; c < 4; ++c){
      int f = fa + c * 512;
      int r = f >> 6, cc = f & 63;
      gload_lds16(A + (size_t)(m0 + r) * K + k0 + cc, &As[buf][wave * 2048 + c * 512]);
    }
    const int fb = wave * 4096 + lane * 8;
    #pragma unroll
    for (int c = 0; c < 8; ++c){
      int f = fb + c * 512;
      int r = f >> 6, cc = f & 63;
      gload_lds16(Wcb + (size_t)r * K + k0 + cc, &Bs[buf][wave * 4096 + c * 512]);
    }
  };

  stage(0, 0);
  __syncthreads();
  int cur = 0;
  for (int kt = 0; kt < 4; ++kt){
    if (kt + 1 < 4) stage(cur ^ 1, kt + 1);
    const u16* as = As[cur];
    const u16* bs = Bs[cur];
    #pragma unroll
    for (int kk = 0; kk < 2; ++kk){
      const int ko = kk * 32 + (lane >> 4) * 8;
      short8 af[4], bm[4], bl[4];
      #pragma unroll
      for (int mi = 0; mi < 4; ++mi)
        af[mi] = *(const short8*)(as + (wm * 64 + mi * 16 + (lane & 15)) * 64 + ko);
      #pragma unroll
      for (int ni = 0; ni < 4; ++ni){
        bm[ni] = *(const short8*)(bs + (wn * 64 + ni * 16 + (lane & 15)) * 64 + ko);
        bl[ni] = *(const short8*)(bs + (128 + wn * 64 + ni * 16 + (lane & 15)) * 64 + ko);
      }
      #pragma unroll
      for (int mi = 0; mi < 4; ++mi)
        #pragma unroll
        for (int ni = 0; ni < 4; ++ni){
          accm[mi][ni] = __builtin_amdgcn_mfma_f32_16x16x32_bf16(af[mi], bm[ni], accm[mi][ni], 0, 0, 0);
          accl[mi][ni] = __builtin_amdgcn_mfma_f32_16x16x32_bf16(af[mi], bl[ni], accl[mi][ni], 0, 0, 0);
        }
    }
    __syncthreads();
    cur ^= 1;
  }

  const int rbase = m0 + wm * 64 + ((lane >> 4) << 2);
  const int cbase = wn * 64 + (lane & 15);
  #pragma unroll
  for (int mi = 0; mi < 4; ++mi){
    #pragma unroll
    for (int ni = 0; ni < 4; ++ni){
      const int col = cbase + ni * 16;
      #pragma unroll
      for (int r = 0; r < 4; ++r){
        const int row = rbase + mi * 16 + r;
        const size_t off = (size_t)row * 128 + col;
        const float m = fmaxf(accm[mi][ni][r], 0.f);
        const float l = fmaxf(accl[mi][ni][r], 0.f);
        outMu[off] = m;
        outLv[off] = l;
        hB[off] = f2bf(eps[off] * expf(l) + m);
      }
    }
  }
}

// ---------- launch ----------
extern "C" void kernel_launch(void* const* d_in, const int* in_sizes, int n_in,
                              void* d_out, int out_size, void* d_ws, size_t ws_size,
                              hipStream_t stream){
  const float* features = (const float*)d_in[0];
  const int*   neigh1   = (const int*)  d_in[1];
  const int*   neigh2   = (const int*)  d_in[2];
  const float* eps      = (const float*)d_in[3];
  const float* W1       = (const float*)d_in[4];
  const float* W2       = (const float*)d_in[5];
  const float* W3       = (const float*)d_in[6];
  const float* Wd1      = (const float*)d_in[7];
  const float* b1       = (const float*)d_in[8];
  const float* Wd2      = (const float*)d_in[9];
  const float* b2       = (const float*)d_in[10];
  const float* M1       = (const float*)d_in[11];
  const float* M2       = (const float*)d_in[12];
  float* out = (float*)d_out;
  char*  ws  = (char*)d_ws;

  // workspace layout (bytes); aliases safe by stream order:
  u16* fB   = (u16*)(ws);
  u16* h1   = fB;                    // alias: fB dead after gather1
  u16* agg1 = (u16*)(ws + 25600000);
  u16* agg2 = agg1;                  // alias: agg1 dead after GEMM1
  u16* hB   = (u16*)(ws + 29794304);
  u16* o1   = (u16*)(ws + 31891456);
  u16* o2   = (u16*)(ws + 36085760);
  u16* tmpb = (u16*)(ws + 40280064);
  u16* W1b  = (u16*)(ws + 51200000);
  u16* Wcb  = W1b  + 65536;   // [W2;W3] 256x256
  u16* Wd1b = Wcb  + 65536;
  u16* Wd2b = Wd1b + 32768;
  u16* M1b  = Wd2b + 65536;
  u16* M2b  = M1b  + 65536;
  u16* Gtb  = M2b  + 65536;   // Gt = M2 @ M1^T

  // 1) converts (one kernel)
  convert_all<<<12852, 256, 0, stream>>>(features, W1, W2, W3, Wd1, Wd2, M1, M2,
                                         fB, W1b, Wcb, Wd1b, Wd2b, M1b, M2b);
  // 2) Gt = M2 @ M1^T   [256x256x256]
  gemm_bt<0,0,0><<<dim3(2,2), 256, 0, stream>>>(M2b, M1b, Gtb, 256, nullptr, 256, 256, 256);
  // 3) agg1 = mean(features[neigh1])  [50000x256] bf16
  gather_mean<<<12500, 256, 0, stream>>>((const u32*)fB, neigh1, (u32*)agg1, 50000);
  // 4) h1 = relu(agg1 @ W1^T)  [50000x256] bf16
  gemm_bt<1,0,0><<<dim3(391,2), 256, 0, stream>>>(agg1, W1b, h1, 256, nullptr, 50000, 256, 256);
  // 5) agg2 = mean(h1[neigh2])  [8192x256] bf16
  gather_mean<<<2048, 256, 0, stream>>>((const u32*)h1, neigh2, (u32*)agg2, 8192);
  // 6) mu,lv -> d_out; h = eps*exp(lv)+mu -> hB   (fused enc+reparam)
  gemm_enc<<<64, 256, 0, stream>>>(agg2, Wcb, eps, out, out + 1048576, hB);
  // 7) o1 = tanh(h @ Wd1^T + b1)  [8192x256] bf16   (K=128)
  gemm_bt<2,0,0><<<dim3(64,2), 256, 0, stream>>>(hB, Wd1b, o1, 256, b1, 8192, 256, 128);
  // 8) o2 = o1 @ Wd2^T + b2  [8192x256] bf16
  gemm_bt<3,0,0><<<dim3(64,2), 256, 0, stream>>>(o1, Wd2b, o2, 256, b2, 8192, 256, 256);
  // 9) tmp = o2 @ Gt^T = o2 @ M1 @ M2^T  [8192x256] bf16
  gemm_bt<0,0,0><<<dim3(64,2), 256, 0, stream>>>(o2, Gtb, tmpb, 256, nullptr, 8192, 256, 256);
  // 10) adj = tmp @ o2^T  [8192x8192] f32, XCD-swizzled
  gemm_bt<0,1,1><<<4096, 256, 0, stream>>>(tmpb, o2, out + 2097152, 8192, nullptr, 8192, 8192, 256);
}

// Round 3
// 263.304 us; speedup vs baseline: 1.0361x; 1.0361x over previous
//
#include <hip/hip_runtime.h>
#include <cstdint>
#include <cstddef>

typedef unsigned short u16;
typedef unsigned int   u32;
typedef __attribute__((ext_vector_type(8))) short short8;
typedef __attribute__((ext_vector_type(8))) u16   u16x8;
typedef __attribute__((ext_vector_type(4))) float f32x4;
typedef __attribute__((ext_vector_type(4))) u16   u16x4;

// ---------- bf16 helpers (RNE) ----------
__device__ __forceinline__ float bf2f(u16 u){
  u32 x = ((u32)u) << 16; float f; __builtin_memcpy(&f, &x, 4); return f;
}
__device__ __forceinline__ u16 f2bf(float f){
  u32 x; __builtin_memcpy(&x, &f, 4);
  x += 0x7fffu + ((x >> 16) & 1u);
  return (u16)(x >> 16);
}

__device__ __forceinline__ void gload_lds16(const u16* g, u16* l){
  __builtin_amdgcn_global_load_lds((const __attribute__((address_space(1))) void*)g,
                                   (__attribute__((address_space(3))) void*)l, 16, 0, 0);
}

// ---------- weight converts (W1, [W2;W3], Wd1, Wd2) : 224 blocks ----------
__global__ void convert_w(const float* __restrict__ W1, const float* __restrict__ W2,
                          const float* __restrict__ W3, const float* __restrict__ Wd1,
                          const float* __restrict__ Wd2,
                          u16* __restrict__ W1b, u16* __restrict__ Wcb,
                          u16* __restrict__ Wd1b, u16* __restrict__ Wd2b){
  int j = blockIdx.x * blockDim.x + threadIdx.x;
  const float* src; u16* dst;
  if (j < 16384)              { src = W1;  dst = W1b; }
  else if ((j -= 16384) < 8192) { src = W2;  dst = Wcb; }
  else if ((j -= 8192)  < 8192) { src = W3;  dst = Wcb + 32768; }
  else if ((j -= 8192)  < 8192) { src = Wd1; dst = Wd1b; }
  else { j -= 8192; src = Wd2; dst = Wd2b; }
  float4 v = ((const float4*)src)[j];
  u16x4 o; o[0]=f2bf(v.x); o[1]=f2bf(v.y); o[2]=f2bf(v.z); o[3]=f2bf(v.w);
  ((u16x4*)dst)[j] = o;
}

// ---------- gather-mean over 20 sampled neighbors (optional relu) ----------
template<int RELU>
__global__ void gather_mean(const u32* __restrict__ rows, const int* __restrict__ idx,
                            u32* __restrict__ out, int nout){
  const int node = blockIdx.x * 4 + (threadIdx.x >> 6);
  const int lane = threadIdx.x & 63;
  if (node >= nout) return;
  const int* ip = idx + (size_t)node * 20;
  const int jv = (lane < 20) ? ip[lane] : 0;
  float a0=0.f, a1=0.f, a2=0.f, a3=0.f;
  #pragma unroll
  for (int s = 0; s < 20; ++s){
    const int j = __shfl(jv, s, 64);
    const uint2 u = *(const uint2*)(rows + (size_t)j * 128 + lane * 2);
    a0 += bf2f((u16)(u.x & 0xffffu)); a1 += bf2f((u16)(u.x >> 16));
    a2 += bf2f((u16)(u.y & 0xffffu)); a3 += bf2f((u16)(u.y >> 16));
  }
  const float inv = 0.05f;
  a0 *= inv; a1 *= inv; a2 *= inv; a3 *= inv;
  if (RELU){ a0=fmaxf(a0,0.f); a1=fmaxf(a1,0.f); a2=fmaxf(a2,0.f); a3=fmaxf(a3,0.f); }
  uint2 o;
  o.x = (u32)f2bf(a0) | ((u32)f2bf(a1) << 16);
  o.y = (u32)f2bf(a2) | ((u32)f2bf(a3) << 16);
  *(uint2*)(out + (size_t)node * 128 + lane * 2) = o;
}

// ---------- MFMA GEMM: C[M,N] = epi(A[M,K] @ B[N,K]^T) ----------
// 128x128 tile, BK=64, 4 waves (2x2 of 64x64), double-buffered.
// AF32/BF32: operand is f32 in global, converted to bf16 during reg-staging.
// EPI: 0=none 1=relu   OUT: 0=bf16  1=f32
template<int EPI, int OUT, int AF32, int BF32>
__global__ __launch_bounds__(256)
void gemm_bt(const void* __restrict__ Av, const void* __restrict__ Bv,
             void* __restrict__ C, int ldc, int M, int N, int K)
{
  __shared__ u16 As[2][8192];
  __shared__ u16 Bs[2][8192];
  const int tid  = threadIdx.x;
  const int lane = tid & 63;
  const int wave = tid >> 6;
  const int wm = wave >> 1, wn = wave & 1;
  const int m0 = blockIdx.x << 7, n0 = blockIdx.y << 7;
  const int nkt = K >> 6;
  const int fbase = wave * 2048 + lane * 8;

  f32x4 acc[4][4];
  #pragma unroll
  for (int a = 0; a < 4; ++a)
    #pragma unroll
    for (int b = 0; b < 4; ++b)
      acc[a][b] = (f32x4){0.f, 0.f, 0.f, 0.f};

  auto stage = [&](int buf, int kt){
    const int k0 = kt * 64;
    if constexpr (AF32){
      const int f = tid * 32;
      int ra = m0 + (f >> 6); if (ra >= M) ra = M - 1;
      const float* sA = (const float*)Av + (size_t)ra * K + k0 + (f & 63);
      u16 t[32];
      #pragma unroll
      for (int q = 0; q < 8; ++q){
        float4 v = *(const float4*)(sA + q * 4);
        t[q*4]=f2bf(v.x); t[q*4+1]=f2bf(v.y); t[q*4+2]=f2bf(v.z); t[q*4+3]=f2bf(v.w);
      }
      #pragma unroll
      for (int q = 0; q < 4; ++q)
        *(u16x8*)(&As[buf][f + q*8]) = *(const u16x8*)(&t[q*8]);
    } else {
      const u16* A = (const u16*)Av;
      #pragma unroll
      for (int c = 0; c < 4; ++c){
        int f = fbase + c * 512;
        int ra = m0 + (f >> 6); if (ra >= M) ra = M - 1;
        gload_lds16(A + (size_t)ra * K + k0 + (f & 63), &As[buf][wave*2048 + c*512]);
      }
    }
    if constexpr (BF32){
      const int f = tid * 32;
      const float* sB = (const float*)Bv + (size_t)(n0 + (f >> 6)) * K + k0 + (f & 63);
      u16 t[32];
      #pragma unroll
      for (int q = 0; q < 8; ++q){
        float4 v = *(const float4*)(sB + q * 4);
        t[q*4]=f2bf(v.x); t[q*4+1]=f2bf(v.y); t[q*4+2]=f2bf(v.z); t[q*4+3]=f2bf(v.w);
      }
      #pragma unroll
      for (int q = 0; q < 4; ++q)
        *(u16x8*)(&Bs[buf][f + q*8]) = *(const u16x8*)(&t[q*8]);
    } else {
      const u16* B = (const u16*)Bv;
      #pragma unroll
      for (int c = 0; c < 4; ++c){
        int f = fbase + c * 512;
        gload_lds16(B + (size_t)(n0 + (f >> 6)) * K + k0 + (f & 63), &Bs[buf][wave*2048 + c*512]);
      }
    }
  };

  stage(0, 0);
  __syncthreads();
  int cur = 0;
  for (int kt = 0; kt < nkt; ++kt){
    if (kt + 1 < nkt) stage(cur ^ 1, kt + 1);
    const u16* as = As[cur];
    const u16* bs = Bs[cur];
    #pragma unroll
    for (int kk = 0; kk < 2; ++kk){
      const int ko = kk * 32 + (lane >> 4) * 8;
      short8 af[4], bq[4];
      #pragma unroll
      for (int mi = 0; mi < 4; ++mi)
        af[mi] = *(const short8*)(as + (wm*64 + mi*16 + (lane & 15)) * 64 + ko);
      #pragma unroll
      for (int ni = 0; ni < 4; ++ni)
        bq[ni] = *(const short8*)(bs + (wn*64 + ni*16 + (lane & 15)) * 64 + ko);
      #pragma unroll
      for (int mi = 0; mi < 4; ++mi)
        #pragma unroll
        for (int ni = 0; ni < 4; ++ni)
          acc[mi][ni] = __builtin_amdgcn_mfma_f32_16x16x32_bf16(af[mi], bq[ni], acc[mi][ni], 0, 0, 0);
    }
    __syncthreads();
    cur ^= 1;
  }

  // epilogue: C/D layout col = lane&15, row = (lane>>4)*4 + reg  [m89-verified]
  const int rbase = m0 + wm * 64 + ((lane >> 4) << 2);
  const int cbase = n0 + wn * 64 + (lane & 15);
  #pragma unroll
  for (int mi = 0; mi < 4; ++mi){
    #pragma unroll
    for (int ni = 0; ni < 4; ++ni){
      const int col = cbase + ni * 16;
      #pragma unroll
      for (int r = 0; r < 4; ++r){
        const int row = rbase + mi * 16 + r;
        if (row < M){
          float v = acc[mi][ni][r];
          if (EPI == 1) v = fmaxf(v, 0.f);
          if (OUT == 0) ((u16*)C)[(size_t)row * ldc + col] = f2bf(v);
          else          ((float*)C)[(size_t)row * ldc + col] = v;
        }
      }
    }
  }
}

// ---------- fused decoder: agg2 -> {mu, logvar, o2, tmp} ----------
// per block: 128 rows. Phases (all row-local):
//   enc:  mu=relu(agg2@W2^T), lv=relu(agg2@W3^T) -> d_out; h=eps*exp(lv)+mu -> LDS
//   D1:   o1 = tanh(h@Wd1^T + b1)                 -> LDS
//   D2:   o2 = o1@Wd2^T + b2                      -> LDS + global (adj B-operand)
//   D3:   tmp = o2@Gt^T                           -> global (adj A-operand)
// LDS 128 KB: SB[0,16384) staging; H[16384,32768) enc-A tile then h/o2-lo chunks;
//             P[32768,65536) o1 chunks then o2-hi chunks.
__global__ __launch_bounds__(256)
void decoder(const u16* __restrict__ agg2, const u16* __restrict__ Wcb,
             const u16* __restrict__ Wd1b, const u16* __restrict__ Wd2b,
             const u16* __restrict__ Gtb, const float* __restrict__ eps,
             const float* __restrict__ b1, const float* __restrict__ b2,
             float* __restrict__ outMu, float* __restrict__ outLv,
             u16* __restrict__ o2g, u16* __restrict__ tmpg)
{
  __shared__ u16 lds[65536];
  u16* SB = lds;
  u16* H  = lds + 16384;
  u16* P  = lds + 32768;
  u16* S0 = SB;
  u16* S1 = SB + 8192;
  const int tid = threadIdx.x;
  const int lane = tid & 63, wave = tid >> 6;
  const int wm = wave >> 1, wn = wave & 1;
  const int m0 = blockIdx.x << 7;
  const int lrbase = wm * 64 + ((lane >> 4) << 2);
  const int cbase  = wn * 64 + (lane & 15);

  auto stage8k = [&](const u16* G, int K, int rowbase, int k0, u16* dst){
    const int fb = wave * 2048 + lane * 8;
    #pragma unroll
    for (int c = 0; c < 4; ++c){
      int f = fb + c * 512;
      gload_lds16(G + (size_t)(rowbase + (f >> 6)) * K + k0 + (f & 63),
                  dst + wave * 2048 + c * 512);
    }
  };
  auto stage16k = [&](const u16* G, int K, int k0, u16* dst){
    const int fb = wave * 4096 + lane * 8;
    #pragma unroll
    for (int c = 0; c < 8; ++c){
      int f = fb + c * 512;
      gload_lds16(G + (size_t)(f >> 6) * K + k0 + (f & 63),
                  dst + wave * 4096 + c * 512);
    }
  };
  auto mstep = [&](const u16* aC, const u16* bT, f32x4 (&acc)[4][4]){
    #pragma unroll
    for (int kk = 0; kk < 2; ++kk){
      const int ko = kk * 32 + (lane >> 4) * 8;
      short8 af[4], bq[4];
      #pragma unroll
      for (int mi = 0; mi < 4; ++mi)
        af[mi] = *(const short8*)(aC + (wm*64 + mi*16 + (lane & 15)) * 64 + ko);
      #pragma unroll
      for (int ni = 0; ni < 4; ++ni)
        bq[ni] = *(const short8*)(bT + (wn*64 + ni*16 + (lane & 15)) * 64 + ko);
      #pragma unroll
      for (int mi = 0; mi < 4; ++mi)
        #pragma unroll
        for (int ni = 0; ni < 4; ++ni)
          acc[mi][ni] = __builtin_amdgcn_mfma_f32_16x16x32_bf16(af[mi], bq[ni], acc[mi][ni], 0, 0, 0);
    }
  };

  // ===== enc =====
  f32x4 accm[4][4], accl[4][4];
  #pragma unroll
  for (int a = 0; a < 4; ++a)
    #pragma unroll
    for (int b = 0; b < 4; ++b){
      accm[a][b] = (f32x4){0.f,0.f,0.f,0.f};
      accl[a][b] = (f32x4){0.f,0.f,0.f,0.f};
    }
  for (int kt = 0; kt < 4; ++kt){
    stage8k(agg2, 256, m0, kt * 64, H);      // A tile into H's first 16 KB
    stage16k(Wcb, 256, kt * 64, SB);         // [W2;W3] tile
    __syncthreads();
    #pragma unroll
    for (int kk = 0; kk < 2; ++kk){
      const int ko = kk * 32 + (lane >> 4) * 8;
      short8 af[4], bm[4], bl[4];
      #pragma unroll
      for (int mi = 0; mi < 4; ++mi)
        af[mi] = *(const short8*)(H + (wm*64 + mi*16 + (lane & 15)) * 64 + ko);
      #pragma unroll
      for (int ni = 0; ni < 4; ++ni){
        bm[ni] = *(const short8*)(SB + (wn*64 + ni*16 + (lane & 15)) * 64 + ko);
        bl[ni] = *(const short8*)(SB + (128 + wn*64 + ni*16 + (lane & 15)) * 64 + ko);
      }
      #pragma unroll
      for (int mi = 0; mi < 4; ++mi)
        #pragma unroll
        for (int ni = 0; ni < 4; ++ni){
          accm[mi][ni] = __builtin_amdgcn_mfma_f32_16x16x32_bf16(af[mi], bm[ni], accm[mi][ni], 0, 0, 0);
          accl[mi][ni] = __builtin_amdgcn_mfma_f32_16x16x32_bf16(af[mi], bl[ni], accl[mi][ni], 0, 0, 0);
        }
    }
    __syncthreads();
  }
  // enc epilogue: mu/lv -> global, h -> H chunked [2][128][64]
  #pragma unroll
  for (int mi = 0; mi < 4; ++mi)
    #pragma unroll
    for (int ni = 0; ni < 4; ++ni){
      const int col = cbase + ni * 16;
      #pragma unroll
      for (int r = 0; r < 4; ++r){
        const int lrow = lrbase + mi * 16 + r;
        const size_t off = (size_t)(m0 + lrow) * 128 + col;
        const float m = fmaxf(accm[mi][ni][r], 0.f);
        const float l = fmaxf(accl[mi][ni][r], 0.f);
        outMu[off] = m;
        outLv[off] = l;
        H[(col >> 6) * 8192 + lrow * 64 + (col & 63)] = f2bf(eps[off] * expf(l) + m);
      }
    }
  __syncthreads();

  // ===== D1: o1 = tanh(h @ Wd1^T + b1), K=128 =====
  for (int nh = 0; nh < 2; ++nh){
    f32x4 acc[4][4];
    #pragma unroll
    for (int a = 0; a < 4; ++a)
      #pragma unroll
      for (int b = 0; b < 4; ++b) acc[a][b] = (f32x4){0.f,0.f,0.f,0.f};
    stage8k(Wd1b, 128, nh * 128, 0, S0);
    __syncthreads();
    stage8k(Wd1b, 128, nh * 128, 64, S1);
    mstep(H, S0, acc);
    __syncthreads();
    mstep(H + 8192, S1, acc);
    __syncthreads();
    #pragma unroll
    for (int mi = 0; mi < 4; ++mi)
      #pragma unroll
      for (int ni = 0; ni < 4; ++ni){
        const int col = nh * 128 + cbase + ni * 16;
        const float bv = b1[col];
        #pragma unroll
        for (int r = 0; r < 4; ++r){
          const int lrow = lrbase + mi * 16 + r;
          P[(col >> 6) * 8192 + lrow * 64 + (col & 63)] = f2bf(tanhf(acc[mi][ni][r] + bv));
        }
      }
  }
  __syncthreads();

  // ===== D2: o2 = o1 @ Wd2^T + b2, K=256, A = P chunks =====
  for (int nh = 0; nh < 2; ++nh){
    f32x4 acc[4][4];
    #pragma unroll
    for (int a = 0; a < 4; ++a)
      #pragma unroll
      for (int b = 0; b < 4; ++b) acc[a][b] = (f32x4){0.f,0.f,0.f,0.f};
    stage8k(Wd2b, 256, nh * 128, 0, S0);
    __syncthreads();
    stage8k(Wd2b, 256, nh * 128, 64, S1);  mstep(P,         S0, acc); __syncthreads();
    stage8k(Wd2b, 256, nh * 128, 128, S0); mstep(P + 8192,  S1, acc); __syncthreads();
    stage8k(Wd2b, 256, nh * 128, 192, S1); mstep(P + 16384, S0, acc); __syncthreads();
    mstep(P + 24576, S1, acc);
    __syncthreads();
    // nh0 -> H chunks 0,1 (cols 0..127); nh1 -> P chunks 0,1 (cols 128..255)
    #pragma unroll
    for (int mi = 0; mi < 4; ++mi)
      #pragma unroll
      for (int ni = 0; ni < 4; ++ni){
        const int col = nh * 128 + cbase + ni * 16;
        const float bv = b2[col];
        #pragma unroll
        for (int r = 0; r < 4; ++r){
          const int lrow = lrbase + mi * 16 + r;
          const u16 v = f2bf(acc[mi][ni][r] + bv);
          if (nh == 0) H[(col >> 6) * 8192 + lrow * 64 + (col & 63)] = v;
          else         P[((col >> 6) - 2) * 8192 + lrow * 64 + (col & 63)] = v;
        }
      }
    __syncthreads();
  }

  // o2 -> global, coalesced (16 B per lane per iter)
  #pragma unroll
  for (int q = 0; q < 16; ++q){
    const int e = q * 2048 + tid * 8;
    const int lrow = e >> 8, col = e & 255;
    const int ch = col >> 6;
    const u16* src = (ch < 2 ? H + ch * 8192 : P + (ch - 2) * 8192) + lrow * 64 + (col & 63);
    *(u16x8*)(o2g + (size_t)(m0 + lrow) * 256 + col) = *(const u16x8*)src;
  }

  // ===== D3: tmp = o2 @ Gt^T, K=256, A = {H0,H1,P0,P1} =====
  const u16* c0 = H;  const u16* c1 = H + 8192;
  const u16* c2 = P;  const u16* c3 = P + 8192;
  for (int nh = 0; nh < 2; ++nh){
    f32x4 acc[4][4];
    #pragma unroll
    for (int a = 0; a < 4; ++a)
      #pragma unroll
      for (int b = 0; b < 4; ++b) acc[a][b] = (f32x4){0.f,0.f,0.f,0.f};
    stage8k(Gtb, 256, nh * 128, 0, S0);
    __syncthreads();
    stage8k(Gtb, 256, nh * 128, 64, S1);  mstep(c0, S0, acc); __syncthreads();
    stage8k(Gtb, 256, nh * 128, 128, S0); mstep(c1, S1, acc); __syncthreads();
    stage8k(Gtb, 256, nh * 128, 192, S1); mstep(c2, S0, acc); __syncthreads();
    mstep(c3, S1, acc);
    #pragma unroll
    for (int mi = 0; mi < 4; ++mi)
      #pragma unroll
      for (int ni = 0; ni < 4; ++ni){
        const int col = nh * 128 + cbase + ni * 16;
        #pragma unroll
        for (int r = 0; r < 4; ++r){
          const int lrow = lrbase + mi * 16 + r;
          tmpg[(size_t)(m0 + lrow) * 256 + col] = f2bf(acc[mi][ni][r]);
        }
      }
    __syncthreads();
  }
}

// ---------- launch ----------
extern "C" void kernel_launch(void* const* d_in, const int* in_sizes, int n_in,
                              void* d_out, int out_size, void* d_ws, size_t ws_size,
                              hipStream_t stream){
  const float* features = (const float*)d_in[0];
  const int*   neigh1   = (const int*)  d_in[1];
  const int*   neigh2   = (const int*)  d_in[2];
  const float* eps      = (const float*)d_in[3];
  const float* W1       = (const float*)d_in[4];
  const float* W2       = (const float*)d_in[5];
  const float* W3       = (const float*)d_in[6];
  const float* Wd1      = (const float*)d_in[7];
  const float* b1       = (const float*)d_in[8];
  const float* Wd2      = (const float*)d_in[9];
  const float* b2       = (const float*)d_in[10];
  const float* M1       = (const float*)d_in[11];
  const float* M2       = (const float*)d_in[12];
  float* out = (float*)d_out;
  char*  ws  = (char*)d_ws;

  // workspace (aliases safe by stream order):
  //  [0, 25.6M)  FW (read by gather1) -> then agg2@0, o2@8M, tmp@16M
  //  [25.6M, 51.2M)  h1
  //  [51.2M, ~51.8M) bf16 weights
  u16* FW   = (u16*)(ws);
  u16* h1   = (u16*)(ws + 25600000);
  u16* agg2 = (u16*)(ws);
  u16* o2g  = (u16*)(ws + 8388608);
  u16* tmpg = (u16*)(ws + 16777216);
  u16* W1b  = (u16*)(ws + 51200000);
  u16* Wcb  = W1b  + 65536;   // [W2;W3] 256x256
  u16* Wd1b = Wcb  + 65536;   // 256x128
  u16* Wd2b = Wd1b + 32768;   // 256x256
  u16* Gtb  = Wd2b + 65536;   // Gt = M2 @ M1^T (256x256)

  // 1) weight converts
  convert_w<<<224, 256, 0, stream>>>(W1, W2, W3, Wd1, Wd2, W1b, Wcb, Wd1b, Wd2b);
  // 2) Gt = M2 @ M1^T (f32 inputs staged+converted in-kernel)
  gemm_bt<0,0,1,1><<<dim3(2,2), 256, 0, stream>>>(M2, M1, Gtb, 256, 256, 256, 256);
  // 3) FW = F @ W1^T  [50000x256] bf16  (A = f32 features, reg-staged)
  gemm_bt<0,0,1,0><<<dim3(391,2), 256, 0, stream>>>(features, W1b, FW, 256, 50000, 256, 256);
  // 4) h1 = relu(mean(FW[neigh1]))  [50000x256]  (linearity: = relu(mean(F[neigh1])@W1^T))
  gather_mean<1><<<12500, 256, 0, stream>>>((const u32*)FW, neigh1, (u32*)h1, 50000);
  // 5) agg2 = mean(h1[neigh2])  [8192x256]
  gather_mean<0><<<2048, 256, 0, stream>>>((const u32*)h1, neigh2, (u32*)agg2, 8192);
  // 6) fused decoder: mu,lv -> d_out; o2, tmp -> ws
  decoder<<<64, 256, 0, stream>>>(agg2, Wcb, Wd1b, Wd2b, Gtb, eps, b1, b2,
                                  out, out + 1048576, o2g, tmpg);
  // 7) adj = tmp @ o2^T  [8192x8192] f32
  gemm_bt<0,1,0,0><<<dim3(64,64), 256, 0, stream>>>(tmpg, o2g, out + 2097152, 8192, 8192, 8192, 256);
}

// Round 5
// 246.091 us; speedup vs baseline: 1.1086x; 1.0699x over previous
//
#include <hip/hip_runtime.h>
#include <cstdint>
#include <cstddef>

typedef unsigned short u16;
typedef unsigned int   u32;
typedef __attribute__((ext_vector_type(8))) short short8;
typedef __attribute__((ext_vector_type(8))) u16   u16x8;
typedef __attribute__((ext_vector_type(4))) float f32x4;
typedef __attribute__((ext_vector_type(4))) u16   u16x4;

// ---------- bf16 helpers (RNE) ----------
__device__ __forceinline__ float bf2f(u16 u){
  u32 x = ((u32)u) << 16; float f; __builtin_memcpy(&f, &x, 4); return f;
}
__device__ __forceinline__ u16 f2bf(float f){
  u32 x; __builtin_memcpy(&x, &f, 4);
  x += 0x7fffu + ((x >> 16) & 1u);
  return (u16)(x >> 16);
}

__device__ __forceinline__ void gload_lds16(const u16* g, u16* l){
  __builtin_amdgcn_global_load_lds((const __attribute__((address_space(1))) void*)g,
                                   (__attribute__((address_space(3))) void*)l, 16, 0, 0);
}

// ---------- weight converts (W1, [W2;W3], Wd1, Wd2) : 224 blocks ----------
__global__ void convert_w(const float* __restrict__ W1, const float* __restrict__ W2,
                          const float* __restrict__ W3, const float* __restrict__ Wd1,
                          const float* __restrict__ Wd2,
                          u16* __restrict__ W1b, u16* __restrict__ Wcb,
                          u16* __restrict__ Wd1b, u16* __restrict__ Wd2b){
  int j = blockIdx.x * blockDim.x + threadIdx.x;
  const float* src; u16* dst;
  if (j < 16384)              { src = W1;  dst = W1b; }
  else if ((j -= 16384) < 8192) { src = W2;  dst = Wcb; }
  else if ((j -= 8192)  < 8192) { src = W3;  dst = Wcb + 32768; }
  else if ((j -= 8192)  < 8192) { src = Wd1; dst = Wd1b; }
  else { j -= 8192; src = Wd2; dst = Wd2b; }
  float4 v = ((const float4*)src)[j];
  u16x4 o; o[0]=f2bf(v.x); o[1]=f2bf(v.y); o[2]=f2bf(v.z); o[3]=f2bf(v.w);
  ((u16x4*)dst)[j] = o;
}

// ---------- gather-mean over 20 sampled neighbors (optional relu) ----------
template<int RELU>
__global__ void gather_mean(const u32* __restrict__ rows, const int* __restrict__ idx,
                            u32* __restrict__ out, int nout){
  const int node = blockIdx.x * 4 + (threadIdx.x >> 6);
  const int lane = threadIdx.x & 63;
  if (node >= nout) return;
  const int* ip = idx + (size_t)node * 20;
  const int jv = (lane < 20) ? ip[lane] : 0;
  float a0=0.f, a1=0.f, a2=0.f, a3=0.f;
  #pragma unroll
  for (int s = 0; s < 20; ++s){
    const int j = __shfl(jv, s, 64);
    const uint2 u = *(const uint2*)(rows + (size_t)j * 128 + lane * 2);
    a0 += bf2f((u16)(u.x & 0xffffu)); a1 += bf2f((u16)(u.x >> 16));
    a2 += bf2f((u16)(u.y & 0xffffu)); a3 += bf2f((u16)(u.y >> 16));
  }
  const float inv = 0.05f;
  a0 *= inv; a1 *= inv; a2 *= inv; a3 *= inv;
  if (RELU){ a0=fmaxf(a0,0.f); a1=fmaxf(a1,0.f); a2=fmaxf(a2,0.f); a3=fmaxf(a3,0.f); }
  uint2 o;
  o.x = (u32)f2bf(a0) | ((u32)f2bf(a1) << 16);
  o.y = (u32)f2bf(a2) | ((u32)f2bf(a3) << 16);
  *(uint2*)(out + (size_t)node * 128 + lane * 2) = o;
}

// ---------- MFMA GEMM: C[M,N] = A[M,K] @ B[N,K]^T ----------
// 128x128 tile, BK=64, 4 waves (2x2 of 64x64), double-buffered.
// AF32/BF32: f32 operands converted to bf16 during reg-staging.
// OUT: 0=bf16 (ldc)  1=f32 (ldc) with LDS-transposed dwordx4 stores (M,N %128==0)
template<int OUT, int AF32, int BF32>
__global__ __launch_bounds__(256)
void gemm_bt(const void* __restrict__ Av, const void* __restrict__ Bv,
             void* __restrict__ C, int ldc, int M, int N, int K)
{
  __shared__ u16 lds[32768];                      // As0|As1|Bs0|Bs1 (8192 u16 each)
  u16* As0 = lds;         u16* As1 = lds + 8192;
  u16* Bs0 = lds + 16384; u16* Bs1 = lds + 24576;
  const int tid  = threadIdx.x;
  const int lane = tid & 63;
  const int wave = tid >> 6;
  const int wm = wave >> 1, wn = wave & 1;
  const int m0 = blockIdx.x << 7, n0 = blockIdx.y << 7;
  const int nkt = K >> 6;
  const int fbase = wave * 2048 + lane * 8;

  f32x4 acc[4][4];
  #pragma unroll
  for (int a = 0; a < 4; ++a)
    #pragma unroll
    for (int b = 0; b < 4; ++b)
      acc[a][b] = (f32x4){0.f, 0.f, 0.f, 0.f};

  auto stage = [&](int buf, int kt){
    const int k0 = kt * 64;
    u16* Ad = buf ? As1 : As0;
    u16* Bd = buf ? Bs1 : Bs0;
    if constexpr (AF32){
      const int f = tid * 32;
      int ra = m0 + (f >> 6); if (ra >= M) ra = M - 1;
      const float* sA = (const float*)Av + (size_t)ra * K + k0 + (f & 63);
      u16 t[32];
      #pragma unroll
      for (int q = 0; q < 8; ++q){
        float4 v = *(const float4*)(sA + q * 4);
        t[q*4]=f2bf(v.x); t[q*4+1]=f2bf(v.y); t[q*4+2]=f2bf(v.z); t[q*4+3]=f2bf(v.w);
      }
      #pragma unroll
      for (int q = 0; q < 4; ++q)
        *(u16x8*)(&Ad[f + q*8]) = *(const u16x8*)(&t[q*8]);
    } else {
      const u16* A = (const u16*)Av;
      #pragma unroll
      for (int c = 0; c < 4; ++c){
        int f = fbase + c * 512;
        int ra = m0 + (f >> 6); if (ra >= M) ra = M - 1;
        gload_lds16(A + (size_t)ra * K + k0 + (f & 63), Ad + wave*2048 + c*512);
      }
    }
    if constexpr (BF32){
      const int f = tid * 32;
      const float* sB = (const float*)Bv + (size_t)(n0 + (f >> 6)) * K + k0 + (f & 63);
      u16 t[32];
      #pragma unroll
      for (int q = 0; q < 8; ++q){
        float4 v = *(const float4*)(sB + q * 4);
        t[q*4]=f2bf(v.x); t[q*4+1]=f2bf(v.y); t[q*4+2]=f2bf(v.z); t[q*4+3]=f2bf(v.w);
      }
      #pragma unroll
      for (int q = 0; q < 4; ++q)
        *(u16x8*)(&Bd[f + q*8]) = *(const u16x8*)(&t[q*8]);
    } else {
      const u16* B = (const u16*)Bv;
      #pragma unroll
      for (int c = 0; c < 4; ++c){
        int f = fbase + c * 512;
        gload_lds16(B + (size_t)(n0 + (f >> 6)) * K + k0 + (f & 63), Bd + wave*2048 + c*512);
      }
    }
  };

  stage(0, 0);
  __syncthreads();
  int cur = 0;
  for (int kt = 0; kt < nkt; ++kt){
    if (kt + 1 < nkt) stage(cur ^ 1, kt + 1);
    const u16* as = cur ? As1 : As0;
    const u16* bs = cur ? Bs1 : Bs0;
    #pragma unroll
    for (int kk = 0; kk < 2; ++kk){
      const int ko = kk * 32 + (lane >> 4) * 8;
      short8 af[4], bq[4];
      #pragma unroll
      for (int mi = 0; mi < 4; ++mi)
        af[mi] = *(const short8*)(as + (wm*64 + mi*16 + (lane & 15)) * 64 + ko);
      #pragma unroll
      for (int ni = 0; ni < 4; ++ni)
        bq[ni] = *(const short8*)(bs + (wn*64 + ni*16 + (lane & 15)) * 64 + ko);
      #pragma unroll
      for (int mi = 0; mi < 4; ++mi)
        #pragma unroll
        for (int ni = 0; ni < 4; ++ni)
          acc[mi][ni] = __builtin_amdgcn_mfma_f32_16x16x32_bf16(af[mi], bq[ni], acc[mi][ni], 0, 0, 0);
    }
    __syncthreads();
    cur ^= 1;
  }

  if constexpr (OUT == 1){
    // LDS-transposed f32 epilogue: 2 halves of 64 rows, padded LD=132 dwords.
    float* T = (float*)lds;
    #pragma unroll
    for (int half = 0; half < 2; ++half){
      if (wm == half){
        #pragma unroll
        for (int mi = 0; mi < 4; ++mi)
          #pragma unroll
          for (int ni = 0; ni < 4; ++ni){
            const int cl = wn*64 + ni*16 + (lane & 15);
            #pragma unroll
            for (int r = 0; r < 4; ++r){
              const int lr = mi*16 + ((lane >> 4) << 2) + r;
              T[lr * 132 + cl] = acc[mi][ni][r];
            }
          }
      }
      __syncthreads();
      #pragma unroll
      for (int q = 0; q < 8; ++q){
        const int e = q * 1024 + tid * 4;
        const int r = e >> 7, c = e & 127;
        float4 v = *(const float4*)(T + r * 132 + c);
        *(float4*)((float*)C + (size_t)(m0 + half*64 + r) * ldc + n0 + c) = v;
      }
      __syncthreads();
    }
  } else {
    const int rbase = m0 + wm * 64 + ((lane >> 4) << 2);
    const int cbase = n0 + wn * 64 + (lane & 15);
    #pragma unroll
    for (int mi = 0; mi < 4; ++mi)
      #pragma unroll
      for (int ni = 0; ni < 4; ++ni){
        const int col = cbase + ni * 16;
        #pragma unroll
        for (int r = 0; r < 4; ++r){
          const int row = rbase + mi * 16 + r;
          if (row < M) ((u16*)C)[(size_t)row * ldc + col] = f2bf(acc[mi][ni][r]);
        }
      }
  }
}

// ---------- FW = F @ W1^T : 128x256 tile (features read ONCE), bf16 out ----------
__global__ __launch_bounds__(256)
void fw_gemm(const float* __restrict__ A, const u16* __restrict__ B,
             u16* __restrict__ C, int M)
{
  __shared__ u16 lds[49152];                 // As 2x8192 (128x64), Bs 2x16384 (256x64)
  u16* As0 = lds;         u16* As1 = lds + 8192;
  u16* Bs0 = lds + 16384; u16* Bs1 = lds + 32768;
  const int tid  = threadIdx.x;
  const int lane = tid & 63;
  const int wave = tid >> 6;
  const int wm = wave >> 1, wn = wave & 1;
  const int m0 = blockIdx.x << 7;

  f32x4 acc[4][8];
  #pragma unroll
  for (int a = 0; a < 4; ++a)
    #pragma unroll
    for (int b = 0; b < 8; ++b)
      acc[a][b] = (f32x4){0.f, 0.f, 0.f, 0.f};

  auto stage = [&](int buf, int kt){
    const int k0 = kt * 64;
    u16* Ad = buf ? As1 : As0;
    u16* Bd = buf ? Bs1 : Bs0;
    const int f = tid * 32;
    int ra = m0 + (f >> 6); if (ra >= M) ra = M - 1;
    const float* sA = A + (size_t)ra * 256 + k0 + (f & 63);
    u16 t[32];
    #pragma unroll
    for (int q = 0; q < 8; ++q){
      float4 v = *(const float4*)(sA + q * 4);
      t[q*4]=f2bf(v.x); t[q*4+1]=f2bf(v.y); t[q*4+2]=f2bf(v.z); t[q*4+3]=f2bf(v.w);
    }
    #pragma unroll
    for (int q = 0; q < 4; ++q)
      *(u16x8*)(&Ad[f + q*8]) = *(const u16x8*)(&t[q*8]);
    const int fb = wave * 4096 + lane * 8;
    #pragma unroll
    for (int c = 0; c < 8; ++c){
      int g = fb + c * 512;
      gload_lds16(B + (size_t)(g >> 6) * 256 + k0 + (g & 63), Bd + wave*4096 + c*512);
    }
  };

  stage(0, 0);
  __syncthreads();
  int cur = 0;
  for (int kt = 0; kt < 4; ++kt){
    if (kt + 1 < 4) stage(cur ^ 1, kt + 1);
    const u16* as = cur ? As1 : As0;
    const u16* bs = cur ? Bs1 : Bs0;
    #pragma unroll
    for (int kk = 0; kk < 2; ++kk){
      const int ko = kk * 32 + (lane >> 4) * 8;
      short8 af[4], bq[8];
      #pragma unroll
      for (int mi = 0; mi < 4; ++mi)
        af[mi] = *(const short8*)(as + (wm*64 + mi*16 + (lane & 15)) * 64 + ko);
      #pragma unroll
      for (int ni = 0; ni < 8; ++ni)
        bq[ni] = *(const short8*)(bs + (wn*128 + ni*16 + (lane & 15)) * 64 + ko);
      #pragma unroll
      for (int mi = 0; mi < 4; ++mi)
        #pragma unroll
        for (int ni = 0; ni < 8; ++ni)
          acc[mi][ni] = __builtin_amdgcn_mfma_f32_16x16x32_bf16(af[mi], bq[ni], acc[mi][ni], 0, 0, 0);
    }
    __syncthreads();
    cur ^= 1;
  }

  const int rbase = m0 + wm * 64 + ((lane >> 4) << 2);
  const int cbase = wn * 128 + (lane & 15);
  #pragma unroll
  for (int mi = 0; mi < 4; ++mi)
    #pragma unroll
    for (int ni = 0; ni < 8; ++ni){
      const int col = cbase + ni * 16;
      #pragma unroll
      for (int r = 0; r < 4; ++r){
        const int row = rbase + mi * 16 + r;
        if (row < M) C[(size_t)row * 256 + col] = f2bf(acc[mi][ni][r]);
      }
    }
}

// ---------- fused decoder: 64 rows/block, 128 blocks ----------
// enc: mu=relu(agg2@W2^T), lv=relu(agg2@W3^T) -> d_out f32; h=eps*exp(lv)+mu -> H
// D1:  o1 = tanh(h@Wd1^T+b1) -> O1 ; D2: o2 = o1@Wd2^T+b2 -> O1(overwrite)+global
// D3:  tmp = o2@Gt^T -> global
__global__ __launch_bounds__(256)
void decoder(const u16* __restrict__ agg2, const u16* __restrict__ Wcb,
             const u16* __restrict__ Wd1b, const u16* __restrict__ Wd2b,
             const u16* __restrict__ Gtb, const float* __restrict__ eps,
             const float* __restrict__ b1, const float* __restrict__ b2,
             float* __restrict__ outMu, float* __restrict__ outLv,
             u16* __restrict__ o2g, u16* __restrict__ tmpg)
{
  __shared__ u16 lds[57344];           // S0 16384 | S1 16384 | H 8192 | O1 16384
  u16* S0 = lds;
  u16* S1 = lds + 16384;
  u16* H  = lds + 32768;               // 2 chunks of 4096 (64x64)
  u16* O1 = lds + 40960;               // 4 chunks of 4096
  u16* A0 = O1;                        // enc A dbuf aliases O1
  u16* A1 = O1 + 4096;
  const int tid = threadIdx.x;
  const int lane = tid & 63, wave = tid >> 6;
  const int m0 = blockIdx.x << 6;

  auto stage16k = [&](const u16* G, int K, int k0, u16* dst){
    const int fb = wave * 4096 + lane * 8;
    #pragma unroll
    for (int c = 0; c < 8; ++c){
      int f = fb + c * 512;
      gload_lds16(G + (size_t)(f >> 6) * K + k0 + (f & 63), dst + wave*4096 + c*512);
    }
  };
  auto stage4k = [&](const u16* G, int k0, u16* dst){
    const int fb = wave * 1024 + lane * 8;
    #pragma unroll
    for (int c = 0; c < 2; ++c){
      int f = fb + c * 512;
      gload_lds16(G + (size_t)(m0 + (f >> 6)) * 256 + k0 + (f & 63), dst + wave*1024 + c*512);
    }
  };
  auto mstep64 = [&](const u16* aC, const u16* bT, f32x4 (&acc)[4][4]){
    #pragma unroll
    for (int kk = 0; kk < 2; ++kk){
      const int ko = kk * 32 + (lane >> 4) * 8;
      short8 af[4], bq[4];
      #pragma unroll
      for (int mi = 0; mi < 4; ++mi)
        af[mi] = *(const short8*)(aC + (mi*16 + (lane & 15)) * 64 + ko);
      #pragma unroll
      for (int ni = 0; ni < 4; ++ni)
        bq[ni] = *(const short8*)(bT + (wave*64 + ni*16 + (lane & 15)) * 64 + ko);
      #pragma unroll
      for (int mi = 0; mi < 4; ++mi)
        #pragma unroll
        for (int ni = 0; ni < 4; ++ni)
          acc[mi][ni] = __builtin_amdgcn_mfma_f32_16x16x32_bf16(af[mi], bq[ni], acc[mi][ni], 0, 0, 0);
    }
  };

  // ===== enc ===== (dual acc: wave covers 32 rows x 64 cols of both mu and lv)
  const int ewm = wave >> 1, ewn = wave & 1;
  f32x4 accm[2][4], accl[2][4];
  #pragma unroll
  for (int a = 0; a < 2; ++a)
    #pragma unroll
    for (int b = 0; b < 4; ++b){
      accm[a][b] = (f32x4){0.f,0.f,0.f,0.f};
      accl[a][b] = (f32x4){0.f,0.f,0.f,0.f};
    }
  {
    stage4k(agg2, 0, A0); stage16k(Wcb, 256, 0, S0);
    __syncthreads();
    for (int kt = 0; kt < 4; ++kt){
      if (kt < 3){
        stage4k(agg2, (kt+1)*64, ((kt+1)&1) ? A1 : A0);
        stage16k(Wcb, 256, (kt+1)*64, ((kt+1)&1) ? S1 : S0);
      }
      const u16* as = (kt & 1) ? A1 : A0;
      const u16* bs = (kt & 1) ? S1 : S0;
      #pragma unroll
      for (int kk = 0; kk < 2; ++kk){
        const int ko = kk * 32 + (lane >> 4) * 8;
        short8 af[2], bm[4], bl[4];
        #pragma unroll
        for (int mi = 0; mi < 2; ++mi)
          af[mi] = *(const short8*)(as + (ewm*32 + mi*16 + (lane & 15)) * 64 + ko);
        #pragma unroll
        for (int ni = 0; ni < 4; ++ni){
          bm[ni] = *(const short8*)(bs + (ewn*64 + ni*16 + (lane & 15)) * 64 + ko);
          bl[ni] = *(const short8*)(bs + (128 + ewn*64 + ni*16 + (lane & 15)) * 64 + ko);
        }
        #pragma unroll
        for (int mi = 0; mi < 2; ++mi)
          #pragma unroll
          for (int ni = 0; ni < 4; ++ni){
            accm[mi][ni] = __builtin_amdgcn_mfma_f32_16x16x32_bf16(af[mi], bm[ni], accm[mi][ni], 0, 0, 0);
            accl[mi][ni] = __builtin_amdgcn_mfma_f32_16x16x32_bf16(af[mi], bl[ni], accl[mi][ni], 0, 0, 0);
          }
      }
      __syncthreads();
    }
  }
  // enc epilogue: mu/lv -> global f32; h -> H chunks [2][64][64] bf16
  {
    const int erb = ewm*32 + ((lane >> 4) << 2);
    const int ecb = ewn*64 + (lane & 15);
    #pragma unroll
    for (int mi = 0; mi < 2; ++mi)
      #pragma unroll
      for (int ni = 0; ni < 4; ++ni){
        const int col = ecb + ni * 16;
        #pragma unroll
        for (int r = 0; r < 4; ++r){
          const int lrow = erb + mi*16 + r;
          const size_t off = (size_t)(m0 + lrow) * 128 + col;
          const float m = fmaxf(accm[mi][ni][r], 0.f);
          const float l = fmaxf(accl[mi][ni][r], 0.f);
          outMu[off] = m;
          outLv[off] = l;
          H[(col >> 6) * 4096 + lrow * 64 + (col & 63)] = f2bf(eps[off] * expf(l) + m);
        }
      }
  }
  // D1 staging overlaps enc epilogue VALU
  stage16k(Wd1b, 128, 0, S0);
  stage16k(Wd1b, 128, 64, S1);
  __syncthreads();

  const int rb = (lane >> 4) << 2;
  const int cb = wave * 64 + (lane & 15);

  // ===== D1: o1 = tanh(h @ Wd1^T + b1), K=128 =====
  {
    f32x4 acc[4][4];
    #pragma unroll
    for (int a = 0; a < 4; ++a)
      #pragma unroll
      for (int b = 0; b < 4; ++b) acc[a][b] = (f32x4){0.f,0.f,0.f,0.f};
    mstep64(H, S0, acc);
    mstep64(H + 4096, S1, acc);
    __syncthreads();
    #pragma unroll
    for (int ni = 0; ni < 4; ++ni){
      const int col = cb + ni * 16;
      const float bv = b1[col];
      #pragma unroll
      for (int mi = 0; mi < 4; ++mi)
        #pragma unroll
        for (int r = 0; r < 4; ++r){
          const int lrow = rb + mi*16 + r;
          O1[(col >> 6) * 4096 + lrow * 64 + (col & 63)] = f2bf(tanhf(acc[mi][ni][r] + bv));
        }
    }
    stage16k(Wd2b, 256, 0, S0);
    __syncthreads();
  }

  // ===== D2: o2 = o1 @ Wd2^T + b2, K=256 =====
  {
    f32x4 acc[4][4];
    #pragma unroll
    for (int a = 0; a < 4; ++a)
      #pragma unroll
      for (int b = 0; b < 4; ++b) acc[a][b] = (f32x4){0.f,0.f,0.f,0.f};
    for (int c = 0; c < 4; ++c){
      if (c < 3) stage16k(Wd2b, 256, (c+1)*64, ((c+1)&1) ? S1 : S0);
      mstep64(O1 + c*4096, (c&1) ? S1 : S0, acc);
      __syncthreads();
    }
    // o2 -> O1 (o1 dead), then coalesced -> global
    #pragma unroll
    for (int ni = 0; ni < 4; ++ni){
      const int col = cb + ni * 16;
      const float bv = b2[col];
      #pragma unroll
      for (int mi = 0; mi < 4; ++mi)
        #pragma unroll
        for (int r = 0; r < 4; ++r){
          const int lrow = rb + mi*16 + r;
          O1[(col >> 6) * 4096 + lrow * 64 + (col & 63)] = f2bf(acc[mi][ni][r] + bv);
        }
    }
    __syncthreads();
    stage16k(Gtb, 256, 0, S0);     // overlap D3 staging with o2g copy
    #pragma unroll
    for (int q = 0; q < 8; ++q){
      const int e = q * 2048 + tid * 8;
      const int lrow = e >> 8, col = e & 255;
      *(u16x8*)(o2g + (size_t)(m0 + lrow) * 256 + col) =
        *(const u16x8*)(O1 + (col >> 6) * 4096 + lrow * 64 + (col & 63));
    }
    __syncthreads();
  }

  // ===== D3: tmp = o2 @ Gt^T, K=256 =====
  {
    f32x4 acc[4][4];
    #pragma unroll
    for (int a = 0; a < 4; ++a)
      #pragma unroll
      for (int b = 0; b < 4; ++b) acc[a][b] = (f32x4){0.f,0.f,0.f,0.f};
    for (int c = 0; c < 4; ++c){
      if (c < 3) stage16k(Gtb, 256, (c+1)*64, ((c+1)&1) ? S1 : S0);
      mstep64(O1 + c*4096, (c&1) ? S1 : S0, acc);
      __syncthreads();
    }
    #pragma unroll
    for (int ni = 0; ni < 4; ++ni){
      const int col = cb + ni * 16;
      #pragma unroll
      for (int mi = 0; mi < 4; ++mi)
        #pragma unroll
        for (int r = 0; r < 4; ++r){
          const int lrow = rb + mi*16 + r;
          tmpg[(size_t)(m0 + lrow) * 256 + col] = f2bf(acc[mi][ni][r]);
        }
    }
  }
}

// ---------- launch ----------
extern "C" void kernel_launch(void* const* d_in, const int* in_sizes, int n_in,
                              void* d_out, int out_size, void* d_ws, size_t ws_size,
                              hipStream_t stream){
  const float* features = (const float*)d_in[0];
  const int*   neigh1   = (const int*)  d_in[1];
  const int*   neigh2   = (const int*)  d_in[2];
  const float* eps      = (const float*)d_in[3];
  const float* W1       = (const float*)d_in[4];
  const float* W2       = (const float*)d_in[5];
  const float* W3       = (const float*)d_in[6];
  const float* Wd1      = (const float*)d_in[7];
  const float* b1       = (const float*)d_in[8];
  const float* Wd2      = (const float*)d_in[9];
  const float* b2       = (const float*)d_in[10];
  const float* M1       = (const float*)d_in[11];
  const float* M2       = (const float*)d_in[12];
  float* out = (float*)d_out;
  char*  ws  = (char*)d_ws;

  u16* FW   = (u16*)(ws);
  u16* h1   = (u16*)(ws + 25600000);
  u16* agg2 = (u16*)(ws);            // aliases FW (dead after gather1)
  u16* o2g  = (u16*)(ws + 8388608);
  u16* tmpg = (u16*)(ws + 16777216);
  u16* W1b  = (u16*)(ws + 51200000);
  u16* Wcb  = W1b  + 65536;   // [W2;W3] 256x256
  u16* Wd1b = Wcb  + 65536;   // 256x128
  u16* Wd2b = Wd1b + 32768;   // 256x256
  u16* Gtb  = Wd2b + 65536;   // Gt = M2 @ M1^T

  // 1) weight converts
  convert_w<<<224, 256, 0, stream>>>(W1, W2, W3, Wd1, Wd2, W1b, Wcb, Wd1b, Wd2b);
  // 2) Gt = M2 @ M1^T (f32 inputs staged+converted in-kernel)
  gemm_bt<0,1,1><<<dim3(2,2), 256, 0, stream>>>(M2, M1, Gtb, 256, 256, 256, 256);
  // 3) FW = F @ W1^T  [50000x256] bf16 (features read once)
  fw_gemm<<<391, 256, 0, stream>>>(features, W1b, FW, 50000);
  // 4) h1 = relu(mean(FW[neigh1]))  [50000x256]
  gather_mean<1><<<12500, 256, 0, stream>>>((const u32*)FW, neigh1, (u32*)h1, 50000);
  // 5) agg2 = mean(h1[neigh2])  [8192x256]
  gather_mean<0><<<2048, 256, 0, stream>>>((const u32*)h1, neigh2, (u32*)agg2, 8192);
  // 6) fused decoder: mu,lv -> d_out; o2, tmp -> ws
  decoder<<<128, 256, 0, stream>>>(agg2, Wcb, Wd1b, Wd2b, Gtb, eps, b1, b2,
                                   out, out + 1048576, o2g, tmpg);
  // 7) adj = tmp @ o2^T  [8192x8192] f32 (LDS-transposed dwordx4 stores)
  gemm_bt<1,0,0><<<dim3(64,64), 256, 0, stream>>>(tmpg, o2g, out + 2097152, 8192, 8192, 8192, 256);
}